// Round 1
// baseline (1817.998 us; speedup 1.0000x reference)
//
#include <hip/hip_runtime.h>
#include <hip/hip_bf16.h>

#define BB_ 64
#define SS_ 50
#define TT_ 25
#define HH_ 1024
#define VV_ 32000

typedef __bf16 bf16x8 __attribute__((ext_vector_type(8)));
typedef float f32x4 __attribute__((ext_vector_type(4)));

__device__ __forceinline__ unsigned short f2b(float f) {
  unsigned u = __float_as_uint(f);
  u = (u + 0x7FFFu + ((u >> 16) & 1u)) >> 16;  // RNE
  return (unsigned short)u;
}
__device__ __forceinline__ float fast_tanh(float x) {
  float e = __expf(2.f * x);
  return 1.f - 2.f / (e + 1.f);
}
__device__ __forceinline__ float fast_sigmoid(float x) {
  return 1.f / (1.f + __expf(-x));
}
__device__ __forceinline__ void gload16(const void* g, void* l) {
  __builtin_amdgcn_global_load_lds((const __attribute__((address_space(1))) void*)g,
                                   (__attribute__((address_space(3))) void*)l, 16, 0, 0);
}
__device__ __forceinline__ bf16x8 ldb8(const unsigned short* p) {
  return *(const bf16x8*)p;
}

// ---------- converts / gathers ----------
__global__ __launch_bounds__(256) void cvt_bf16(const float* __restrict__ src,
                                                unsigned short* __restrict__ dst, long n) {
  long i = ((long)blockIdx.x * 256 + threadIdx.x) * 4;
  if (i >= n) return;
  float4 v = *(const float4*)(src + i);
  *(ushort4*)(dst + i) = make_ushort4(f2b(v.x), f2b(v.y), f2b(v.z), f2b(v.w));
}

__global__ __launch_bounds__(256) void embed_gather(const int* __restrict__ tgt,
                                                    const float* __restrict__ emb,
                                                    unsigned short* __restrict__ X) {
  long idx = ((long)blockIdx.x * 256 + threadIdx.x) * 4;
  if (idx >= (long)1600 * HH_) return;
  int col = (int)(idx & (HH_ - 1));
  int r = (int)(idx >> 10);          // row = b*25 + t
  int t = r % 25;
  int tok = (t == 0) ? 1 : tgt[r - 1];   // SOS=1; tgt flat [B,T]
  float4 v = *(const float4*)(emb + (long)tok * HH_ + col);
  *(ushort4*)(X + idx) = make_ushort4(f2b(v.x), f2b(v.y), f2b(v.z), f2b(v.w));
}

__global__ __launch_bounds__(256) void init_h(const float* __restrict__ eh,
                                              float* __restrict__ Hf,
                                              unsigned short* __restrict__ Hb) {
  int i = (blockIdx.x * 256 + threadIdx.x) * 4;
  if (i >= BB_ * HH_) return;
  float4 v = *(const float4*)(eh + i);
  *(float4*)(Hf + i) = v;
  *(ushort4*)(Hb + i) = make_ushort4(f2b(v.x), f2b(v.y), f2b(v.z), f2b(v.w));
}

// ---------- big GEMM: out[M x ldo] = A[Mpad x 1024](bf16) @ W[N x ldw]^T + bias ----------
// m97 structure: 128x128 tile, BK=32, global_load_lds(16B), 4 waves each 64x64.
__global__ __launch_bounds__(256) void gemm128_bt(
    const unsigned short* __restrict__ A, const unsigned short* __restrict__ W,
    const float* __restrict__ bias, float* __restrict__ out, long ldo,
    int Mtiles, int ldw, int Mvalid) {
  __shared__ __align__(16) unsigned short As[128 * 32];
  __shared__ __align__(16) unsigned short Bs[128 * 32];
  int bid = blockIdx.x;
  int m0 = (bid % Mtiles) * 128;   // m fastest: consecutive blocks share W chunk
  int n0 = (bid / Mtiles) * 128;
  int tid = threadIdx.x;
  int w = tid >> 6, l = tid & 63;
  int srow = tid >> 2, scg = tid & 3;
  int mw = (w & 1) * 64, nw = (w >> 1) * 64;

  const unsigned short* Ag0 = A + (long)(m0 + srow) * 1024 + scg * 8;
  const unsigned short* Ag1 = Ag0 + 64 * 1024;
  const unsigned short* Wg0 = W + (long)(n0 + srow) * ldw + scg * 8;
  const unsigned short* Wg1 = Wg0 + (long)64 * ldw;
  unsigned short* lA0 = As + tid * 8;
  unsigned short* lA1 = As + 2048 + tid * 8;
  unsigned short* lB0 = Bs + tid * 8;
  unsigned short* lB1 = Bs + 2048 + tid * 8;

  f32x4 zero = {0.f, 0.f, 0.f, 0.f};
  f32x4 acc[4][4];
#pragma unroll
  for (int i = 0; i < 4; ++i)
#pragma unroll
    for (int j = 0; j < 4; ++j) acc[i][j] = zero;

  for (int k0 = 0; k0 < 1024; k0 += 32) {
    __syncthreads();
    gload16(Ag0 + k0, lA0);
    gload16(Ag1 + k0, lA1);
    gload16(Wg0 + k0, lB0);
    gload16(Wg1 + k0, lB1);
    __syncthreads();
    bf16x8 af[4], bg[4];
#pragma unroll
    for (int mt = 0; mt < 4; ++mt)
      af[mt] = ldb8(As + (mw + mt * 16 + (l & 15)) * 32 + (l >> 4) * 8);
#pragma unroll
    for (int nt = 0; nt < 4; ++nt)
      bg[nt] = ldb8(Bs + (nw + nt * 16 + (l & 15)) * 32 + (l >> 4) * 8);
#pragma unroll
    for (int mt = 0; mt < 4; ++mt)
#pragma unroll
      for (int nt = 0; nt < 4; ++nt)
        acc[mt][nt] = __builtin_amdgcn_mfma_f32_16x16x32_bf16(af[mt], bg[nt], acc[mt][nt], 0, 0, 0);
  }

  int lr = (l >> 4) * 4, lc = l & 15;
#pragma unroll
  for (int nt = 0; nt < 4; ++nt) {
    int col = n0 + nw + nt * 16 + lc;
    float bv = bias[col];
#pragma unroll
    for (int mt = 0; mt < 4; ++mt) {
#pragma unroll
      for (int r = 0; r < 4; ++r) {
        int m = m0 + mw + mt * 16 + lr + r;
        if (m < Mvalid) out[(long)m * ldo + col] = acc[mt][nt][r] + bv;
      }
    }
  }
}

// ---------- per-step: q = h@Wa^T + ba ; gh = h@W_hh^T + b_hh ----------
// wave-per-16x16-tile, direct global fragments (weights stream from L2/L3).
__global__ __launch_bounds__(256) void step_qgh(
    const unsigned short* __restrict__ Hb, const unsigned short* __restrict__ WaB,
    const unsigned short* __restrict__ WhhB, const float* __restrict__ ba,
    const float* __restrict__ bhh, float* __restrict__ Q, float* __restrict__ GH) {
  int gw = (int)((blockIdx.x * blockDim.x + threadIdx.x) >> 6);  // 0..1023
  int l = threadIdx.x & 63;
  int m0 = (gw & 3) * 16;
  int n = (gw >> 2) * 16;  // 0..4080 over [q:1024 | gh:3072]
  const unsigned short* Wp;
  const float* bp;
  float* op;
  long ldo;
  if (n < 1024) { Wp = WaB + (long)n * 1024; bp = ba + n; op = Q + n; ldo = 1024; }
  else { int n2 = n - 1024; Wp = WhhB + (long)n2 * 1024; bp = bhh + n2; op = GH + n2; ldo = 3072; }
  const unsigned short* Ap = Hb + (long)(m0 + (l & 15)) * 1024 + (l >> 4) * 8;
  const unsigned short* Bp = Wp + (long)(l & 15) * 1024 + (l >> 4) * 8;
  f32x4 acc = {0.f, 0.f, 0.f, 0.f};
#pragma unroll 4
  for (int k = 0; k < 1024; k += 32)
    acc = __builtin_amdgcn_mfma_f32_16x16x32_bf16(ldb8(Ap + k), ldb8(Bp + k), acc, 0, 0, 0);
  int lc = l & 15, lr = (l >> 4) * 4;
  float bv = bp[lc];
#pragma unroll
  for (int r = 0; r < 4; ++r) op[(long)(m0 + lr + r) * ldo + lc] = acc[r] + bv;
}

// ---------- per-step attention: scores->softmax->context (fp32) ----------
__global__ __launch_bounds__(512) void step_attn(
    const float* __restrict__ Q, const float* __restrict__ KEYS,
    const float* __restrict__ Va, const float* __restrict__ enc,
    float* __restrict__ CTX, unsigned short* __restrict__ Cb) {
  int b = blockIdx.x;
  int tid = threadIdx.x, w = tid >> 6, l = tid & 63;
  __shared__ float sc[64];
  __shared__ float wgt[64];
  const float* q = Q + (long)b * HH_;
  const float* kbase = KEYS + (long)b * SS_ * HH_;
  for (int s = w; s < SS_; s += 8) {
    const float* kr = kbase + (long)s * HH_;
    float p = 0.f;
#pragma unroll
    for (int j = 0; j < 16; ++j) {
      int hh = l + j * 64;
      p += fast_tanh(q[hh] + kr[hh]) * Va[hh];
    }
#pragma unroll
    for (int off = 32; off; off >>= 1) p += __shfl_down(p, off);
    if (l == 0) sc[s] = p;
  }
  __syncthreads();
  if (tid < 64) {  // softmax over 50 in wave 0 (bv shift cancels)
    float v = (tid < SS_) ? sc[tid] : -1e30f;
    float m = v;
#pragma unroll
    for (int off = 32; off; off >>= 1) m = fmaxf(m, __shfl_down(m, off));
    m = __shfl(m, 0);
    float e = (tid < SS_) ? __expf(v - m) : 0.f;
    float ssum = e;
#pragma unroll
    for (int off = 32; off; off >>= 1) ssum += __shfl_down(ssum, off);
    ssum = __shfl(ssum, 0);
    if (tid < SS_) wgt[tid] = e / ssum;
  }
  __syncthreads();
  for (int c = tid; c < HH_; c += 512) {
    float a0 = 0.f;
    const float* ep = enc + (long)b * SS_ * HH_ + c;
#pragma unroll 10
    for (int s = 0; s < SS_; ++s) a0 += wgt[s] * ep[(long)s * HH_];
    CTX[(long)b * HH_ + c] = a0;
    Cb[(long)b * HH_ + c] = f2b(a0);
  }
}

// ---------- per-step: gx_ctx GEMM (3 gates) + GRU fusion -> h_new ----------
__global__ __launch_bounds__(256) void step_gru(
    const unsigned short* __restrict__ Cb, const unsigned short* __restrict__ WihB,
    const float* __restrict__ GA, const float* __restrict__ GH,
    float* __restrict__ Hf, unsigned short* __restrict__ Hb,
    unsigned short* __restrict__ HALL, int t) {
  int gw = (int)((blockIdx.x * blockDim.x + threadIdx.x) >> 6);  // 0..255
  int l = threadIdx.x & 63;
  int m0 = (gw & 3) * 16;
  int n0 = (gw >> 2) * 16;
  const unsigned short* Ap = Cb + (long)(m0 + (l & 15)) * 1024 + (l >> 4) * 8;
  const unsigned short* B0 = WihB + (long)(n0 + (l & 15)) * 2048 + 1024 + (l >> 4) * 8;
  const unsigned short* B1 = B0 + (long)1024 * 2048;
  const unsigned short* B2 = B0 + (long)2048 * 2048;
  f32x4 ar = {0.f, 0.f, 0.f, 0.f}, az = ar, an = ar;
#pragma unroll 4
  for (int k = 0; k < 1024; k += 32) {
    bf16x8 a = ldb8(Ap + k);
    ar = __builtin_amdgcn_mfma_f32_16x16x32_bf16(a, ldb8(B0 + k), ar, 0, 0, 0);
    az = __builtin_amdgcn_mfma_f32_16x16x32_bf16(a, ldb8(B1 + k), az, 0, 0, 0);
    an = __builtin_amdgcn_mfma_f32_16x16x32_bf16(a, ldb8(B2 + k), an, 0, 0, 0);
  }
  int lc = l & 15, lr = (l >> 4) * 4;
  int i = n0 + lc;
#pragma unroll
  for (int r = 0; r < 4; ++r) {
    int bb = m0 + lr + r;
    long rowBT = (long)bb * 25 + t;
    const float* ga = GA + rowBT * 3072;
    const float* gh = GH + (long)bb * 3072;
    float rr = fast_sigmoid(ga[i] + ar[r] + gh[i]);
    float zz = fast_sigmoid(ga[1024 + i] + az[r] + gh[1024 + i]);
    float nn = fast_tanh(ga[2048 + i] + an[r] + rr * gh[2048 + i]);
    float hold = Hf[(long)bb * 1024 + i];
    float hnew = (1.f - zz) * nn + zz * hold;
    Hf[(long)bb * 1024 + i] = hnew;
    unsigned short hb = f2b(hnew);
    Hb[(long)bb * 1024 + i] = hb;
    HALL[rowBT * 1024 + i] = hb;
  }
}

extern "C" void kernel_launch(void* const* d_in, const int* in_sizes, int n_in,
                              void* d_out, int out_size, void* d_ws, size_t ws_size,
                              hipStream_t stream) {
  (void)in_sizes; (void)n_in; (void)out_size; (void)ws_size;
  const float* enc  = (const float*)d_in[0];
  const float* ehid = (const float*)d_in[1];
  const int*   tgt  = (const int*)d_in[2];
  const float* emb  = (const float*)d_in[3];
  const float* Wa   = (const float*)d_in[4];
  const float* ba   = (const float*)d_in[5];
  const float* Ua   = (const float*)d_in[6];
  const float* bu   = (const float*)d_in[7];
  const float* Va   = (const float*)d_in[8];
  const float* Wih  = (const float*)d_in[10];
  const float* bih  = (const float*)d_in[11];
  const float* Whh  = (const float*)d_in[12];
  const float* bhh  = (const float*)d_in[13];
  const float* Wout = (const float*)d_in[14];
  const float* bout = (const float*)d_in[15];
  float* out = (float*)d_out;

  char* p = (char*)d_ws;
  auto alloc = [&](size_t bytes) { char* r = p; p += (bytes + 255) & ~(size_t)255; return r; };
  unsigned short* WOUTB = (unsigned short*)alloc((size_t)VV_ * HH_ * 2);
  unsigned short* WIHB  = (unsigned short*)alloc((size_t)3072 * 2048 * 2);
  unsigned short* WHHB  = (unsigned short*)alloc((size_t)3072 * 1024 * 2);
  unsigned short* WAB   = (unsigned short*)alloc((size_t)1024 * 1024 * 2);
  unsigned short* UAB   = (unsigned short*)alloc((size_t)1024 * 1024 * 2);
  unsigned short* ENCB  = (unsigned short*)alloc((size_t)BB_ * SS_ * HH_ * 2);
  unsigned short* XEMB  = (unsigned short*)alloc((size_t)1664 * HH_ * 2);  // pad 1600->1664
  unsigned short* HALLB = (unsigned short*)alloc((size_t)1664 * HH_ * 2);
  float* KEYS = (float*)alloc((size_t)BB_ * SS_ * HH_ * 4);
  float* GA   = (float*)alloc((size_t)1600 * 3072 * 4);
  float* GHf  = (float*)alloc((size_t)BB_ * 3072 * 4);
  float* Qf   = (float*)alloc((size_t)BB_ * HH_ * 4);
  float* Hf   = (float*)alloc((size_t)BB_ * HH_ * 4);
  unsigned short* Hb = (unsigned short*)alloc((size_t)BB_ * HH_ * 2);
  float* CTX  = (float*)alloc((size_t)BB_ * HH_ * 4);
  unsigned short* CTXB = (unsigned short*)alloc((size_t)BB_ * HH_ * 2);

  auto cvt = [&](const float* s, unsigned short* d, long n) {
    cvt_bf16<<<dim3((unsigned)((n / 4 + 255) / 256)), dim3(256), 0, stream>>>(s, d, n);
  };
  cvt(Wout, WOUTB, (long)VV_ * HH_);
  cvt(Wih, WIHB, (long)3072 * 2048);
  cvt(Whh, WHHB, (long)3072 * 1024);
  cvt(Wa, WAB, (long)1024 * 1024);
  cvt(Ua, UAB, (long)1024 * 1024);
  cvt(enc, ENCB, (long)BB_ * SS_ * HH_);
  embed_gather<<<dim3(1600 * HH_ / 4 / 256), dim3(256), 0, stream>>>(tgt, emb, XEMB);
  init_h<<<dim3(BB_ * HH_ / 4 / 256), dim3(256), 0, stream>>>(ehid, Hf, Hb);

  // keys_proj = enc @ Ua^T + bu : [3200,1024]
  gemm128_bt<<<dim3(25 * 8), dim3(256), 0, stream>>>(ENCB, UAB, bu, KEYS, (long)1024, 25, 1024, 3200);
  // gA = Xemb @ W_ih[:, :H]^T + b_ih : [1600,3072]
  gemm128_bt<<<dim3(13 * 24), dim3(256), 0, stream>>>(XEMB, WIHB, bih, GA, (long)3072, 13, 2048, 1600);

  for (int t = 0; t < TT_; ++t) {
    step_qgh<<<dim3(256), dim3(256), 0, stream>>>(Hb, WAB, WHHB, ba, bhh, Qf, GHf);
    step_attn<<<dim3(64), dim3(512), 0, stream>>>(Qf, KEYS, Va, enc, CTX, CTXB);
    step_gru<<<dim3(64), dim3(256), 0, stream>>>(CTXB, WIHB, GA, GHf, Hf, Hb, HALLB, t);
  }

  // logits = Hall @ Wout^T + bout, rows are (b*25+t) -> out[B,T,V] directly
  gemm128_bt<<<dim3(13 * 250), dim3(256), 0, stream>>>(HALLB, WOUTB, bout, out, (long)VV_, 13, 1024, 1600);
}